// Round 17
// baseline (310.296 us; speedup 1.0000x reference)
//
#include <hip/hip_runtime.h>
#include <float.h>

// Problem constants: x (2,128,64,64) fp32, w (256,256) fp32, b (256,) fp32
// out (2,256,64,64) fp32. K=9 nearest neighbors on normalized features.
constexpr int CB = 2;       // batch
constexpr int CC = 128;     // channels
constexpr int CN = 4096;    // points (64*64)
constexpr int NSPLIT = 16;  // knn col-splits

typedef unsigned long long u64;
typedef unsigned int u32;

// ---- workspace layout (float offsets), total ~15.4 MB ----
// r16 BUG: W planes are 3x65536 ushort = 98304 FLOATS (not 49152); OFF_A=65536
// overlapped them -> wprep clobbered xh groups 0..47 (b=0, n<768) -> absmax 3.9.
// Lifetimes: x-planes (prep -> knn,pq), W-planes (wprep -> pq),
// PK (knn -> merge), Q (pq -> gather) OVERLAYS PK (merge precedes pq).
constexpr size_t OFF_SQ = 0;                         // [B][N] sum(xn^2)        8192 f
constexpr size_t OFF_RN = 8192;                      // [B][N] norm             8192 f
constexpr size_t OFF_WP = 16384;                     // W planes 3x65536 ushort 98304 f
constexpr size_t OFF_A  = 114688;                    // x planes 3x1048576 ushort = 1572864 f
constexpr size_t OFF_PK = OFF_A + 1572864;           // PK 1572864 u32 | Q 2097152 f (overlay)
constexpr size_t OFF_NN = OFF_PK + 2097152;          // [B][N][9] int           73728
// total 3,858,432 floats ~= 15.4 MB (< r2-r8's proven ~17.1 MB ws)

typedef __attribute__((ext_vector_type(8))) short bf16x8;
typedef __attribute__((ext_vector_type(4))) float f32x4;

__device__ __forceinline__ unsigned short f2bf(float f) {
    u32 u = __float_as_uint(f);
    u32 r = (u + 0x7FFFu + ((u >> 16) & 1u)) >> 16;   // round-nearest-even
    return (unsigned short)r;
}
__device__ __forceinline__ float bf2f(unsigned short h) {
    return __uint_as_float(((u32)h) << 16);
}

// ---- u64-key top-9 machinery (r14/r15-proven) ----
// Key = mono(score)<<12 | (4095-j): larger key == better under the EXACT
// jax.lax.top_k order (score desc, index asc). Keys unique (j unique).
__device__ __forceinline__ u32 mono32(float v) {
    u32 u = __float_as_uint(v);
    u32 m = (u32)((int)u >> 31);
    return u ^ (m | 0x80000000u);
}
__device__ __forceinline__ u64 make_key(float v, int jg) {
    return ((u64)mono32(v) << 12) | (u32)(4095 - jg);
}
// sk sorted DESCENDING (sk[8]=min); unconditional bubble pass.
__device__ __forceinline__ void key_insert(u64 (&sk)[9], u64 key) {
    u64 t = key;
#pragma unroll
    for (int k = 0; k < 9; ++k) {
        const bool gt = t > sk[k];
        const u64 hi = gt ? t : sk[k];
        t = gt ? sk[k] : t;
        sk[k] = hi;
    }
}
__device__ __forceinline__ void key_init(u64 (&sk)[9]) {
#pragma unroll
    for (int k = 0; k < 9; ++k) sk[k] = (u64)(8 - k);   // descending sentinels
}

// ---- Kernel A: normalize + sq + rn + bf16x3 x-planes (fragment-major) ----
// plane[b][g=n>>4][q=c>>3][r=n&15][e=c&7]: frag load = contiguous 1KiB/wave.
__global__ __launch_bounds__(256) void prep_kernel(const float* __restrict__ x,
                                                   float* __restrict__ sqv,
                                                   float* __restrict__ rnv,
                                                   unsigned short* __restrict__ xh,
                                                   unsigned short* __restrict__ xm,
                                                   unsigned short* __restrict__ xl) {
    __shared__ float XT[128][65];
    __shared__ float red[4][64];
    __shared__ float invl[64];
    const int b = blockIdx.y, n0 = blockIdx.x * 64;
    const int tid = threadIdx.x;
    const int nl = tid & 63, c0 = tid >> 6;
#pragma unroll 4
    for (int cc = 0; cc < 32; ++cc) {
        int c = cc * 4 + c0;
        XT[c][nl] = x[((size_t)(b * 128 + c)) * 4096 + n0 + nl];
    }
    __syncthreads();
    {
        float acc = 0.f;
#pragma unroll 4
        for (int cc = 0; cc < 32; ++cc) { float v = XT[c0 * 32 + cc][nl]; acc += v * v; }
        red[c0][nl] = acc;
    }
    __syncthreads();
    if (tid < 64) {
        float ss = red[0][tid] + red[1][tid] + red[2][tid] + red[3][tid] + 1e-12f;
        float sr = sqrtf(ss);
        invl[tid] = 1.0f / sr;
        rnv[b * 4096 + n0 + tid] = sr;
    }
    __syncthreads();
    {
        float acc = 0.f;
        float iv = invl[nl];
#pragma unroll 4
        for (int cc = 0; cc < 32; ++cc) {
            int c = cc * 4 + c0;
            float v = XT[c][nl] * iv;
            XT[c][nl] = v;
            acc += v * v;
        }
        red[c0][nl] = acc;
    }
    __syncthreads();
    if (tid < 64) {
        sqv[b * 4096 + n0 + tid] = red[0][tid] + red[1][tid] + red[2][tid] + red[3][tid];
    }
    __syncthreads();
    {
        const int n = tid & 63, cq = tid >> 6;
        unsigned short hs[32], ms[32], ls[32];
#pragma unroll
        for (int cc = 0; cc < 32; ++cc) {
            float v = XT[cq * 32 + cc][n];
            unsigned short h = f2bf(v);  float hf = bf2f(h);
            float r1 = v - hf;
            unsigned short m = f2bf(r1); float mf = bf2f(m);
            unsigned short l = f2bf(r1 - mf);
            hs[cc] = h; ms[cc] = m; ls[cc] = l;
        }
        const int g = (n0 >> 4) + (n >> 4), r = n & 15;
        const size_t gb = ((size_t)(b * 256 + g)) * 2048 + r * 8;
#pragma unroll
        for (int u = 0; u < 4; ++u) {
            const size_t off = gb + (size_t)(cq * 4 + u) * 128;
            *(float4*)&xh[off] = *(const float4*)&hs[u * 8];
            *(float4*)&xm[off] = *(const float4*)&ms[u * 8];
            *(float4*)&xl[off] = *(const float4*)&ls[u * 8];
        }
    }
}

// ---- Kernel W: packed WT = (W1-W2 | W2)^T, bf16x3 split, fragment-major ----
// wplane[g=o'>>4][q=c>>3][r=o'&15][e=c&7]
__global__ __launch_bounds__(256) void wprep_kernel(const float* __restrict__ w,
                                                    unsigned short* __restrict__ wh,
                                                    unsigned short* __restrict__ wm,
                                                    unsigned short* __restrict__ wl) {
    int id = blockIdx.x * 256 + threadIdx.x;   // 65536 = 128*512
    int c = id >> 9, o = id & 511;
    float v;
    if (o < 256) v = w[o * 256 + c] - w[o * 256 + 128 + c];
    else         v = w[(o - 256) * 256 + 128 + c];
    unsigned short h = f2bf(v);  float hf = bf2f(h);
    float r1 = v - hf;
    unsigned short m = f2bf(r1); float mf = bf2f(m);
    unsigned short l = f2bf(r1 - mf);
    const size_t off = (size_t)(o >> 4) * 2048 + (c >> 3) * 128 + (o & 15) * 8 + (c & 7);
    wh[off] = h; wm[off] = m; wl[off] = l;
}

// ---- Kernel B v16: MFMA bf16x3 Gram, sorted-chain register scan ----
// __launch_bounds__(256, 8): VGPR_Count was exactly 64 (the 8-waves/SIMD
// boundary) -> cap changes nothing in allocation but doubles residency to
// 8 blocks/CU (LDS 18432*8 = 147K <= 160K; grid 2048 = exactly 8/CU).
__global__ __launch_bounds__(256, 8) void knn_kernel(const unsigned short* __restrict__ xh,
                                                     const unsigned short* __restrict__ xm,
                                                     const unsigned short* __restrict__ xl,
                                                     const float* __restrict__ sqv,
                                                     u32* __restrict__ pk) {
    __shared__ u64 MK[2304];                   // 18,432 B: [256][9] keys

    const int b  = blockIdx.z;
    const int i0 = blockIdx.y * 64;
    const int js = blockIdx.x;                 // 0..15, cols js*256 .. +255
    const int tid = threadIdx.x;
    const int lane = tid & 63, w = tid >> 6;
    const int l15 = lane & 15, l4 = lane >> 4;

    const size_t ib0 = ((size_t)(b * 256 + (i0 >> 4) + w)) * 2048;
    u64 sk[9];
    key_init(sk);

    for (int tt = 0; tt < 4; ++tt) {
        const int t = (tt + w) & 3;            // stagger: waves desynchronized
        const int jt = js * 256 + t * 64;
        const size_t jb0 = ((size_t)(b * 256 + (jt >> 4))) * 2048;  // + Y*2048
        f32x4 a0 = {0.f, 0.f, 0.f, 0.f}, a1 = a0, a2 = a0, a3 = a0;

#pragma unroll
        for (int ch = 0; ch < 4; ++ch) {       // K chunks of 32; no barriers
            const int koff = (ch * 4 + l4) * 128 + l15 * 8;   // shorts, 1KiB/wave
            const bf16x8 ih = *(const bf16x8*)(xh + ib0 + koff);
            const bf16x8 im = *(const bf16x8*)(xm + ib0 + koff);
            const bf16x8 il = *(const bf16x8*)(xl + ib0 + koff);
#define DO_Y(ACC, Y)                                                          \
            {                                                                 \
                const bf16x8 jh = *(const bf16x8*)(xh + jb0 + (Y) * 2048 + koff); \
                const bf16x8 jm = *(const bf16x8*)(xm + jb0 + (Y) * 2048 + koff); \
                const bf16x8 jl = *(const bf16x8*)(xl + jb0 + (Y) * 2048 + koff); \
                ACC = __builtin_amdgcn_mfma_f32_16x16x32_bf16(jh, ih, ACC, 0, 0, 0); \
                ACC = __builtin_amdgcn_mfma_f32_16x16x32_bf16(jh, im, ACC, 0, 0, 0); \
                ACC = __builtin_amdgcn_mfma_f32_16x16x32_bf16(jm, ih, ACC, 0, 0, 0); \
                ACC = __builtin_amdgcn_mfma_f32_16x16x32_bf16(jm, im, ACC, 0, 0, 0); \
                ACC = __builtin_amdgcn_mfma_f32_16x16x32_bf16(jh, il, ACC, 0, 0, 0); \
                ACC = __builtin_amdgcn_mfma_f32_16x16x32_bf16(jl, ih, ACC, 0, 0, 0); \
            }
            DO_Y(a0, 0) DO_Y(a1, 1) DO_Y(a2, 2) DO_Y(a3, 3)
#undef DO_Y
        }
#define SCAN_Y(ACC, Y)                                                        \
        {                                                                     \
            const int jb4 = jt + (Y) * 16 + l4 * 4;                           \
            const float4 sq4 = *(const float4*)&sqv[b * 4096 + jb4];          \
            key_insert(sk, make_key(fmaf(2.0f, ACC[0], -sq4.x), jb4 + 0));    \
            key_insert(sk, make_key(fmaf(2.0f, ACC[1], -sq4.y), jb4 + 1));    \
            key_insert(sk, make_key(fmaf(2.0f, ACC[2], -sq4.z), jb4 + 2));    \
            key_insert(sk, make_key(fmaf(2.0f, ACC[3], -sq4.w), jb4 + 3));    \
        }
        SCAN_Y(a0, 0) SCAN_Y(a1, 1) SCAN_Y(a2, 2) SCAN_Y(a3, 3)
#undef SCAN_Y
    }
    // merge: i-row (w*16 + l15) has 4 disjoint-j lists at lanes {l15 + 16*l4}
#pragma unroll
    for (int k = 0; k < 9; ++k) MK[tid * 9 + k] = sk[k];
    __syncthreads();
    if (tid < 64) {                            // i = i0 + tid
        u64 mk[9];
        key_init(mk);
        const int wsrc = tid >> 4, r = tid & 15;
        for (int q2 = 0; q2 < 4; ++q2) {
            const int src = wsrc * 64 + q2 * 16 + r;
            for (int k = 0; k < 9; ++k) key_insert(mk, MK[src * 9 + k]);
        }
        // compress: 9 mono-scores + 9 x 8-bit local-j in 3 words (exact)
        u32 ow[12];
        u32 iw0 = 0, iw1 = 0, iw2 = 0;
#pragma unroll
        for (int k = 0; k < 9; ++k) {
            ow[k] = (u32)(mk[k] >> 12);
            u32 lj = (u32)((4095 - (int)(mk[k] & 4095)) - js * 256) & 255u;
            if (k < 4)      iw0 |= lj << (k * 8);
            else if (k < 8) iw1 |= lj << ((k - 4) * 8);
            else            iw2 |= lj;
        }
        ow[9] = iw0; ow[10] = iw1; ow[11] = iw2;
        const size_t base = ((size_t)(b * 4096 + i0 + tid) * NSPLIT + js) * 12;
        *(uint4*)&pk[base]     = *(const uint4*)&ow[0];
        *(uint4*)&pk[base + 4] = *(const uint4*)&ow[4];
        *(uint4*)&pk[base + 8] = *(const uint4*)&ow[8];
    }
}

// ---- Kernel M: merge 16 split-lists -> final 9 indices; 2 threads/row ----
__global__ __launch_bounds__(256) void merge_kernel(const u32* __restrict__ pk,
                                                    int* __restrict__ nn) {
    const int gt = blockIdx.x * 256 + threadIdx.x;   // 16384 threads
    const int row = gt >> 1, half = gt & 1;
    u64 mk[9];
    key_init(mk);
    for (int s = half * 8; s < half * 8 + 8; ++s) {
        const u32* p = pk + ((size_t)row * NSPLIT + s) * 12;
        u32 ow[12];
        *(uint4*)&ow[0] = *(const uint4*)&p[0];
        *(uint4*)&ow[4] = *(const uint4*)&p[4];
        *(uint4*)&ow[8] = *(const uint4*)&p[8];
        const u32 iw[3] = {ow[9], ow[10], ow[11]};
#pragma unroll
        for (int k = 0; k < 9; ++k) {
            const int lj = (int)((iw[k >> 2] >> ((k & 3) * 8)) & 255u);
            const int jg = s * 256 + lj;
            key_insert(mk, ((u64)ow[k] << 12) | (u32)(4095 - jg));
        }
    }
    // exchange partner's 9 keys (adjacent lane) and fold in
    u64 tmp[9];
#pragma unroll
    for (int k = 0; k < 9; ++k) tmp[k] = __shfl_xor(mk[k], 1);
#pragma unroll
    for (int k = 0; k < 9; ++k) key_insert(mk, tmp[k]);
    if (half == 0) {
#pragma unroll
        for (int k = 0; k < 9; ++k) nn[row * 9 + k] = 4095 - (int)(mk[k] & 4095);
    }
}

// ---- Kernel C v2: P/Q GEMM via MFMA bf16x3 (barrier-free, no LDS) ----
// mfma(W, X): D row = W-row = o' ((lane>>4)*4+reg), col = X-row = n (lane&15)
// [orientation HW-verified r10-r15]. value = acc * rn[n] (xn*rn reconstruction,
// proven r2-r14). P (o'<256) -> out[b][o'][n] scalar stores; Q (o'>=256) ->
// q[b][n][o'-256] contiguous float4. Wave = 32 o' x 32 n (2x2 tiles, 16f acc).
__global__ __launch_bounds__(256, 4) void pq_kernel(const unsigned short* __restrict__ xh,
                                                    const unsigned short* __restrict__ xm,
                                                    const unsigned short* __restrict__ xl,
                                                    const unsigned short* __restrict__ wh,
                                                    const unsigned short* __restrict__ wm,
                                                    const unsigned short* __restrict__ wl,
                                                    const float* __restrict__ rnv,
                                                    float* __restrict__ q,
                                                    float* __restrict__ out) {
    const int b  = blockIdx.z;
    const int n0 = blockIdx.x * 64;
    const int o0 = blockIdx.y * 64;
    const int tid = threadIdx.x;
    const int lane = tid & 63, w = tid >> 6;
    const int l15 = lane & 15, l4 = lane >> 4;
    const int nw = n0 + (w & 1) * 32;
    const int ow = o0 + (w >> 1) * 32;

    const size_t xg = ((size_t)(b * 256 + (nw >> 4))) * 2048;   // + tn*2048
    const size_t wg = ((size_t)(ow >> 4)) * 2048;               // + to*2048

    f32x4 a00 = {0.f, 0.f, 0.f, 0.f}, a01 = a00, a10 = a00, a11 = a00;  // [to][tn]

#pragma unroll
    for (int ch = 0; ch < 4; ++ch) {
        const int koff = (ch * 4 + l4) * 128 + l15 * 8;
        const bf16x8 x0h = *(const bf16x8*)(xh + xg + koff);
        const bf16x8 x0m = *(const bf16x8*)(xm + xg + koff);
        const bf16x8 x0l = *(const bf16x8*)(xl + xg + koff);
        const bf16x8 x1h = *(const bf16x8*)(xh + xg + 2048 + koff);
        const bf16x8 x1m = *(const bf16x8*)(xm + xg + 2048 + koff);
        const bf16x8 x1l = *(const bf16x8*)(xl + xg + 2048 + koff);
        const bf16x8 w0h = *(const bf16x8*)(wh + wg + koff);
        const bf16x8 w0m = *(const bf16x8*)(wm + wg + koff);
        const bf16x8 w0l = *(const bf16x8*)(wl + wg + koff);
        const bf16x8 w1h = *(const bf16x8*)(wh + wg + 2048 + koff);
        const bf16x8 w1m = *(const bf16x8*)(wm + wg + 2048 + koff);
        const bf16x8 w1l = *(const bf16x8*)(wl + wg + 2048 + koff);
#define PROD(ACC, WH, WM, WL, XH, XM, XL)                                     \
        ACC = __builtin_amdgcn_mfma_f32_16x16x32_bf16(WH, XH, ACC, 0, 0, 0);  \
        ACC = __builtin_amdgcn_mfma_f32_16x16x32_bf16(WH, XM, ACC, 0, 0, 0);  \
        ACC = __builtin_amdgcn_mfma_f32_16x16x32_bf16(WM, XH, ACC, 0, 0, 0);  \
        ACC = __builtin_amdgcn_mfma_f32_16x16x32_bf16(WM, XM, ACC, 0, 0, 0);  \
        ACC = __builtin_amdgcn_mfma_f32_16x16x32_bf16(WH, XL, ACC, 0, 0, 0);  \
        ACC = __builtin_amdgcn_mfma_f32_16x16x32_bf16(WL, XH, ACC, 0, 0, 0);
        PROD(a00, w0h, w0m, w0l, x0h, x0m, x0l)
        PROD(a01, w0h, w0m, w0l, x1h, x1m, x1l)
        PROD(a10, w1h, w1m, w1l, x0h, x0m, x0l)
        PROD(a11, w1h, w1m, w1l, x1h, x1m, x1l)
#undef PROD
    }
#define EPI(ACC, TO, TN)                                                      \
    {                                                                         \
        const int ob = ow + (TO) * 16 + l4 * 4;                               \
        const int n  = nw + (TN) * 16 + l15;                                  \
        const float rn = rnv[b * 4096 + n];                                   \
        if (ob < 256) {                                                       \
            out[((size_t)(b * 256 + ob + 0)) * 4096 + n] = ACC[0] * rn;       \
            out[((size_t)(b * 256 + ob + 1)) * 4096 + n] = ACC[1] * rn;       \
            out[((size_t)(b * 256 + ob + 2)) * 4096 + n] = ACC[2] * rn;       \
            out[((size_t)(b * 256 + ob + 3)) * 4096 + n] = ACC[3] * rn;       \
        } else {                                                              \
            float4 v = make_float4(ACC[0] * rn, ACC[1] * rn,                  \
                                   ACC[2] * rn, ACC[3] * rn);                 \
            *(float4*)&q[((size_t)(b * 4096 + n)) * 256 + (ob - 256)] = v;    \
        }                                                                     \
    }
    EPI(a00, 0, 0) EPI(a01, 0, 1) EPI(a10, 1, 0) EPI(a11, 1, 1)
#undef EPI
}

// ---- Kernel D: out = relu(P(out) + bias + max_k Q[nn]) in place ----
__global__ __launch_bounds__(256) void gather_kernel(const float* __restrict__ q,
                                                     const int* __restrict__ nn,
                                                     const float* __restrict__ bias,
                                                     float* __restrict__ out) {
    __shared__ int idx[32][9];
    const int b = blockIdx.y, n0 = blockIdx.x * 32;
    const int tid = threadIdx.x;
    for (int t = tid; t < 288; t += 256) {
        int pt = t / 9, k = t - pt * 9;
        idx[pt][k] = nn[(b * 4096 + n0 + pt) * 9 + k];
    }
    __syncthreads();
    const float bv = bias[tid];
    const size_t orow = ((size_t)(b * 256 + tid)) * 4096 + n0;
    float pvals[32];
#pragma unroll
    for (int u = 0; u < 8; ++u)
        *(float4*)&pvals[u * 4] = *(const float4*)&out[orow + u * 4];
    float val[32];
#pragma unroll
    for (int pt = 0; pt < 32; ++pt) {
        float m = -FLT_MAX;
#pragma unroll
        for (int k = 0; k < 9; ++k) {
            int j = idx[pt][k] & 4095;
            m = fmaxf(m, q[((size_t)(b * 4096 + j)) * 256 + tid]);
        }
        float vv = pvals[pt] + bv + m;
        val[pt] = vv > 0.f ? vv : 0.f;
    }
#pragma unroll
    for (int u = 0; u < 8; ++u) {
        float4 v = make_float4(val[u * 4], val[u * 4 + 1], val[u * 4 + 2], val[u * 4 + 3]);
        *(float4*)&out[orow + u * 4] = v;
    }
}

extern "C" void kernel_launch(void* const* d_in, const int* in_sizes, int n_in,
                              void* d_out, int out_size, void* d_ws, size_t ws_size,
                              hipStream_t stream) {
    const float* x    = (const float*)d_in[0];
    const float* w    = (const float*)d_in[1];
    const float* bias = (const float*)d_in[2];
    float* ws = (float*)d_ws;
    float* sq = ws + OFF_SQ;
    float* rn = ws + OFF_RN;
    unsigned short* wh = (unsigned short*)(ws + OFF_WP);
    unsigned short* wm = wh + 65536;
    unsigned short* wl = wm + 65536;
    unsigned short* xh = (unsigned short*)(ws + OFF_A);
    unsigned short* xm = xh + (size_t)CB * CN * CC;
    unsigned short* xl = xm + (size_t)CB * CN * CC;
    u32*   pk = (u32*)(ws + OFF_PK);
    float* q  = ws + OFF_PK;                    // overlays PK (merge precedes pq)
    int*   nn = (int*)(ws + OFF_NN);
    float* out = (float*)d_out;

    prep_kernel  <<<dim3(64, 2),     256, 0, stream>>>(x, sq, rn, xh, xm, xl);
    wprep_kernel <<<dim3(256),       256, 0, stream>>>(w, wh, wm, wl);
    knn_kernel   <<<dim3(16, 64, 2), 256, 0, stream>>>(xh, xm, xl, sq, pk);
    merge_kernel <<<dim3(64),        256, 0, stream>>>(pk, nn);
    pq_kernel    <<<dim3(64, 8, 2),  256, 0, stream>>>(xh, xm, xl, wh, wm, wl, rn, q, out);
    gather_kernel<<<dim3(128, 2),    256, 0, stream>>>(q, nn, bias, out);
}

// Round 18
// 158.437 us; speedup vs baseline: 1.9585x; 1.9585x over previous
//
#include <hip/hip_runtime.h>
#include <float.h>

// Problem constants: x (2,128,64,64) fp32, w (256,256) fp32, b (256,) fp32
// out (2,256,64,64) fp32. K=9 nearest neighbors on normalized features.
constexpr int CB = 2;       // batch
constexpr int CC = 128;     // channels
constexpr int CN = 4096;    // points (64*64)
constexpr int NSPLIT = 16;  // knn col-splits

typedef unsigned long long u64;
typedef unsigned int u32;

// ---- workspace layout (float offsets), total ~15.4 MB ----
// Lifetimes: x-planes (prep -> knn,pq), W-planes (wprep -> pq),
// PK (knn -> merge), Q (pq -> gather) OVERLAYS PK (merge precedes pq).
constexpr size_t OFF_SQ = 0;                         // [B][N] sum(xn^2)        8192 f
constexpr size_t OFF_RN = 8192;                      // [B][N] norm             8192 f
constexpr size_t OFF_WP = 16384;                     // W planes 3x65536 ushort 98304 f
constexpr size_t OFF_A  = 114688;                    // x planes 3x1048576 ushort = 1572864 f
constexpr size_t OFF_PK = OFF_A + 1572864;           // PK 1572864 u32 | Q 2097152 f (overlay)
constexpr size_t OFF_NN = OFF_PK + 2097152;          // [B][N][9] int           73728

typedef __attribute__((ext_vector_type(8))) short bf16x8;
typedef __attribute__((ext_vector_type(4))) float f32x4;

__device__ __forceinline__ unsigned short f2bf(float f) {
    u32 u = __float_as_uint(f);
    u32 r = (u + 0x7FFFu + ((u >> 16) & 1u)) >> 16;   // round-nearest-even
    return (unsigned short)r;
}
__device__ __forceinline__ float bf2f(unsigned short h) {
    return __uint_as_float(((u32)h) << 16);
}

// ---- u64-key top-9 machinery (r14/r15-proven) ----
// Key = mono(score)<<12 | (4095-j): larger key == better under the EXACT
// jax.lax.top_k order (score desc, index asc). Keys unique (j unique).
__device__ __forceinline__ u32 mono32(float v) {
    u32 u = __float_as_uint(v);
    u32 m = (u32)((int)u >> 31);
    return u ^ (m | 0x80000000u);
}
__device__ __forceinline__ u64 make_key(float v, int jg) {
    return ((u64)mono32(v) << 12) | (u32)(4095 - jg);
}
// sk sorted DESCENDING (sk[8]=min); unconditional bubble pass.
__device__ __forceinline__ void key_insert(u64 (&sk)[9], u64 key) {
    u64 t = key;
#pragma unroll
    for (int k = 0; k < 9; ++k) {
        const bool gt = t > sk[k];
        const u64 hi = gt ? t : sk[k];
        t = gt ? sk[k] : t;
        sk[k] = hi;
    }
}
__device__ __forceinline__ void key_init(u64 (&sk)[9]) {
#pragma unroll
    for (int k = 0; k < 9; ++k) sk[k] = (u64)(8 - k);   // descending sentinels
}

// ---- Kernel A: normalize + sq + rn + bf16x3 x-planes (fragment-major) ----
// plane[b][g=n>>4][q=c>>3][r=n&15][e=c&7]: frag load = contiguous 1KiB/wave.
__global__ __launch_bounds__(256) void prep_kernel(const float* __restrict__ x,
                                                   float* __restrict__ sqv,
                                                   float* __restrict__ rnv,
                                                   unsigned short* __restrict__ xh,
                                                   unsigned short* __restrict__ xm,
                                                   unsigned short* __restrict__ xl) {
    __shared__ float XT[128][65];
    __shared__ float red[4][64];
    __shared__ float invl[64];
    const int b = blockIdx.y, n0 = blockIdx.x * 64;
    const int tid = threadIdx.x;
    const int nl = tid & 63, c0 = tid >> 6;
#pragma unroll 4
    for (int cc = 0; cc < 32; ++cc) {
        int c = cc * 4 + c0;
        XT[c][nl] = x[((size_t)(b * 128 + c)) * 4096 + n0 + nl];
    }
    __syncthreads();
    {
        float acc = 0.f;
#pragma unroll 4
        for (int cc = 0; cc < 32; ++cc) { float v = XT[c0 * 32 + cc][nl]; acc += v * v; }
        red[c0][nl] = acc;
    }
    __syncthreads();
    if (tid < 64) {
        float ss = red[0][tid] + red[1][tid] + red[2][tid] + red[3][tid] + 1e-12f;
        float sr = sqrtf(ss);
        invl[tid] = 1.0f / sr;
        rnv[b * 4096 + n0 + tid] = sr;
    }
    __syncthreads();
    {
        float acc = 0.f;
        float iv = invl[nl];
#pragma unroll 4
        for (int cc = 0; cc < 32; ++cc) {
            int c = cc * 4 + c0;
            float v = XT[c][nl] * iv;
            XT[c][nl] = v;
            acc += v * v;
        }
        red[c0][nl] = acc;
    }
    __syncthreads();
    if (tid < 64) {
        sqv[b * 4096 + n0 + tid] = red[0][tid] + red[1][tid] + red[2][tid] + red[3][tid];
    }
    __syncthreads();
    {
        const int n = tid & 63, cq = tid >> 6;
        unsigned short hs[32], ms[32], ls[32];
#pragma unroll
        for (int cc = 0; cc < 32; ++cc) {
            float v = XT[cq * 32 + cc][n];
            unsigned short h = f2bf(v);  float hf = bf2f(h);
            float r1 = v - hf;
            unsigned short m = f2bf(r1); float mf = bf2f(m);
            unsigned short l = f2bf(r1 - mf);
            hs[cc] = h; ms[cc] = m; ls[cc] = l;
        }
        const int g = (n0 >> 4) + (n >> 4), r = n & 15;
        const size_t gb = ((size_t)(b * 256 + g)) * 2048 + r * 8;
#pragma unroll
        for (int u = 0; u < 4; ++u) {
            const size_t off = gb + (size_t)(cq * 4 + u) * 128;
            *(float4*)&xh[off] = *(const float4*)&hs[u * 8];
            *(float4*)&xm[off] = *(const float4*)&ms[u * 8];
            *(float4*)&xl[off] = *(const float4*)&ls[u * 8];
        }
    }
}

// ---- Kernel W: packed WT = (W1-W2 | W2)^T, bf16x3 split, fragment-major ----
// wplane[g=o'>>4][q=c>>3][r=o'&15][e=c&7]
__global__ __launch_bounds__(256) void wprep_kernel(const float* __restrict__ w,
                                                    unsigned short* __restrict__ wh,
                                                    unsigned short* __restrict__ wm,
                                                    unsigned short* __restrict__ wl) {
    int id = blockIdx.x * 256 + threadIdx.x;   // 65536 = 128*512
    int c = id >> 9, o = id & 511;
    float v;
    if (o < 256) v = w[o * 256 + c] - w[o * 256 + 128 + c];
    else         v = w[(o - 256) * 256 + 128 + c];
    unsigned short h = f2bf(v);  float hf = bf2f(h);
    float r1 = v - hf;
    unsigned short m = f2bf(r1); float mf = bf2f(m);
    unsigned short l = f2bf(r1 - mf);
    const size_t off = (size_t)(o >> 4) * 2048 + (c >> 3) * 128 + (o & 15) * 8 + (c & 7);
    wh[off] = h; wm[off] = m; wl[off] = l;
}

// ---- Kernel B v18: MFMA bf16x3 Gram, sorted-chain register scan ----
// __launch_bounds__(256, 4): r17 PROVED (256,8) starves the unified VGPR file
// (VGPR_Count fell to 32; 509MB FETCH + 594MB WRITE of scratch spill; knn
// 122->280us despite 68% occupancy). (256,4) = r15's proven point: VGPR 64,
// zero spill, knn 122us. Occupancy bought by register starvation is negative.
__global__ __launch_bounds__(256, 4) void knn_kernel(const unsigned short* __restrict__ xh,
                                                     const unsigned short* __restrict__ xm,
                                                     const unsigned short* __restrict__ xl,
                                                     const float* __restrict__ sqv,
                                                     u32* __restrict__ pk) {
    __shared__ u64 MK[2304];                   // 18,432 B: [256][9] keys

    const int b  = blockIdx.z;
    const int i0 = blockIdx.y * 64;
    const int js = blockIdx.x;                 // 0..15, cols js*256 .. +255
    const int tid = threadIdx.x;
    const int lane = tid & 63, w = tid >> 6;
    const int l15 = lane & 15, l4 = lane >> 4;

    const size_t ib0 = ((size_t)(b * 256 + (i0 >> 4) + w)) * 2048;
    u64 sk[9];
    key_init(sk);

    for (int tt = 0; tt < 4; ++tt) {
        const int t = (tt + w) & 3;            // stagger: waves desynchronized
        const int jt = js * 256 + t * 64;
        const size_t jb0 = ((size_t)(b * 256 + (jt >> 4))) * 2048;  // + Y*2048
        f32x4 a0 = {0.f, 0.f, 0.f, 0.f}, a1 = a0, a2 = a0, a3 = a0;

#pragma unroll
        for (int ch = 0; ch < 4; ++ch) {       // K chunks of 32; no barriers
            const int koff = (ch * 4 + l4) * 128 + l15 * 8;   // shorts, 1KiB/wave
            const bf16x8 ih = *(const bf16x8*)(xh + ib0 + koff);
            const bf16x8 im = *(const bf16x8*)(xm + ib0 + koff);
            const bf16x8 il = *(const bf16x8*)(xl + ib0 + koff);
#define DO_Y(ACC, Y)                                                          \
            {                                                                 \
                const bf16x8 jh = *(const bf16x8*)(xh + jb0 + (Y) * 2048 + koff); \
                const bf16x8 jm = *(const bf16x8*)(xm + jb0 + (Y) * 2048 + koff); \
                const bf16x8 jl = *(const bf16x8*)(xl + jb0 + (Y) * 2048 + koff); \
                ACC = __builtin_amdgcn_mfma_f32_16x16x32_bf16(jh, ih, ACC, 0, 0, 0); \
                ACC = __builtin_amdgcn_mfma_f32_16x16x32_bf16(jh, im, ACC, 0, 0, 0); \
                ACC = __builtin_amdgcn_mfma_f32_16x16x32_bf16(jm, ih, ACC, 0, 0, 0); \
                ACC = __builtin_amdgcn_mfma_f32_16x16x32_bf16(jm, im, ACC, 0, 0, 0); \
                ACC = __builtin_amdgcn_mfma_f32_16x16x32_bf16(jh, il, ACC, 0, 0, 0); \
                ACC = __builtin_amdgcn_mfma_f32_16x16x32_bf16(jl, ih, ACC, 0, 0, 0); \
            }
            DO_Y(a0, 0) DO_Y(a1, 1) DO_Y(a2, 2) DO_Y(a3, 3)
#undef DO_Y
        }
#define SCAN_Y(ACC, Y)                                                        \
        {                                                                     \
            const int jb4 = jt + (Y) * 16 + l4 * 4;                           \
            const float4 sq4 = *(const float4*)&sqv[b * 4096 + jb4];          \
            key_insert(sk, make_key(fmaf(2.0f, ACC[0], -sq4.x), jb4 + 0));    \
            key_insert(sk, make_key(fmaf(2.0f, ACC[1], -sq4.y), jb4 + 1));    \
            key_insert(sk, make_key(fmaf(2.0f, ACC[2], -sq4.z), jb4 + 2));    \
            key_insert(sk, make_key(fmaf(2.0f, ACC[3], -sq4.w), jb4 + 3));    \
        }
        SCAN_Y(a0, 0) SCAN_Y(a1, 1) SCAN_Y(a2, 2) SCAN_Y(a3, 3)
#undef SCAN_Y
    }
    // merge: i-row (w*16 + l15) has 4 disjoint-j lists at lanes {l15 + 16*l4}
#pragma unroll
    for (int k = 0; k < 9; ++k) MK[tid * 9 + k] = sk[k];
    __syncthreads();
    if (tid < 64) {                            // i = i0 + tid
        u64 mk[9];
        key_init(mk);
        const int wsrc = tid >> 4, r = tid & 15;
        for (int q2 = 0; q2 < 4; ++q2) {
            const int src = wsrc * 64 + q2 * 16 + r;
            for (int k = 0; k < 9; ++k) key_insert(mk, MK[src * 9 + k]);
        }
        // compress: 9 mono-scores + 9 x 8-bit local-j in 3 words (exact)
        u32 ow[12];
        u32 iw0 = 0, iw1 = 0, iw2 = 0;
#pragma unroll
        for (int k = 0; k < 9; ++k) {
            ow[k] = (u32)(mk[k] >> 12);
            u32 lj = (u32)((4095 - (int)(mk[k] & 4095)) - js * 256) & 255u;
            if (k < 4)      iw0 |= lj << (k * 8);
            else if (k < 8) iw1 |= lj << ((k - 4) * 8);
            else            iw2 |= lj;
        }
        ow[9] = iw0; ow[10] = iw1; ow[11] = iw2;
        const size_t base = ((size_t)(b * 4096 + i0 + tid) * NSPLIT + js) * 12;
        *(uint4*)&pk[base]     = *(const uint4*)&ow[0];
        *(uint4*)&pk[base + 4] = *(const uint4*)&ow[4];
        *(uint4*)&pk[base + 8] = *(const uint4*)&ow[8];
    }
}

// ---- Kernel M: merge 16 split-lists -> final 9 indices; 2 threads/row ----
__global__ __launch_bounds__(256) void merge_kernel(const u32* __restrict__ pk,
                                                    int* __restrict__ nn) {
    const int gt = blockIdx.x * 256 + threadIdx.x;   // 16384 threads
    const int row = gt >> 1, half = gt & 1;
    u64 mk[9];
    key_init(mk);
    for (int s = half * 8; s < half * 8 + 8; ++s) {
        const u32* p = pk + ((size_t)row * NSPLIT + s) * 12;
        u32 ow[12];
        *(uint4*)&ow[0] = *(const uint4*)&p[0];
        *(uint4*)&ow[4] = *(const uint4*)&p[4];
        *(uint4*)&ow[8] = *(const uint4*)&p[8];
        const u32 iw[3] = {ow[9], ow[10], ow[11]};
#pragma unroll
        for (int k = 0; k < 9; ++k) {
            const int lj = (int)((iw[k >> 2] >> ((k & 3) * 8)) & 255u);
            const int jg = s * 256 + lj;
            key_insert(mk, ((u64)ow[k] << 12) | (u32)(4095 - jg));
        }
    }
    // exchange partner's 9 keys (adjacent lane) and fold in
    u64 tmp[9];
#pragma unroll
    for (int k = 0; k < 9; ++k) tmp[k] = __shfl_xor(mk[k], 1);
#pragma unroll
    for (int k = 0; k < 9; ++k) key_insert(mk, tmp[k]);
    if (half == 0) {
#pragma unroll
        for (int k = 0; k < 9; ++k) nn[row * 9 + k] = 4095 - (int)(mk[k] & 4095);
    }
}

// ---- Kernel C v2: P/Q GEMM via MFMA bf16x3 (barrier-free, no LDS) ----
// mfma(W, X): D row = W-row = o' ((lane>>4)*4+reg), col = X-row = n (lane&15)
// [orientation HW-verified r10-r15]. value = acc * rn[n]. P (o'<256) ->
// out[b][o'][n] scalar stores; Q (o'>=256) -> q[b][n][o'-256] float4.
__global__ __launch_bounds__(256, 4) void pq_kernel(const unsigned short* __restrict__ xh,
                                                    const unsigned short* __restrict__ xm,
                                                    const unsigned short* __restrict__ xl,
                                                    const unsigned short* __restrict__ wh,
                                                    const unsigned short* __restrict__ wm,
                                                    const unsigned short* __restrict__ wl,
                                                    const float* __restrict__ rnv,
                                                    float* __restrict__ q,
                                                    float* __restrict__ out) {
    const int b  = blockIdx.z;
    const int n0 = blockIdx.x * 64;
    const int o0 = blockIdx.y * 64;
    const int tid = threadIdx.x;
    const int lane = tid & 63, w = tid >> 6;
    const int l15 = lane & 15, l4 = lane >> 4;
    const int nw = n0 + (w & 1) * 32;
    const int ow = o0 + (w >> 1) * 32;

    const size_t xg = ((size_t)(b * 256 + (nw >> 4))) * 2048;   // + tn*2048
    const size_t wg = ((size_t)(ow >> 4)) * 2048;               // + to*2048

    f32x4 a00 = {0.f, 0.f, 0.f, 0.f}, a01 = a00, a10 = a00, a11 = a00;  // [to][tn]

#pragma unroll
    for (int ch = 0; ch < 4; ++ch) {
        const int koff = (ch * 4 + l4) * 128 + l15 * 8;
        const bf16x8 x0h = *(const bf16x8*)(xh + xg + koff);
        const bf16x8 x0m = *(const bf16x8*)(xm + xg + koff);
        const bf16x8 x0l = *(const bf16x8*)(xl + xg + koff);
        const bf16x8 x1h = *(const bf16x8*)(xh + xg + 2048 + koff);
        const bf16x8 x1m = *(const bf16x8*)(xm + xg + 2048 + koff);
        const bf16x8 x1l = *(const bf16x8*)(xl + xg + 2048 + koff);
        const bf16x8 w0h = *(const bf16x8*)(wh + wg + koff);
        const bf16x8 w0m = *(const bf16x8*)(wm + wg + koff);
        const bf16x8 w0l = *(const bf16x8*)(wl + wg + koff);
        const bf16x8 w1h = *(const bf16x8*)(wh + wg + 2048 + koff);
        const bf16x8 w1m = *(const bf16x8*)(wm + wg + 2048 + koff);
        const bf16x8 w1l = *(const bf16x8*)(wl + wg + 2048 + koff);
#define PROD(ACC, WH, WM, WL, XH, XM, XL)                                     \
        ACC = __builtin_amdgcn_mfma_f32_16x16x32_bf16(WH, XH, ACC, 0, 0, 0);  \
        ACC = __builtin_amdgcn_mfma_f32_16x16x32_bf16(WH, XM, ACC, 0, 0, 0);  \
        ACC = __builtin_amdgcn_mfma_f32_16x16x32_bf16(WM, XH, ACC, 0, 0, 0);  \
        ACC = __builtin_amdgcn_mfma_f32_16x16x32_bf16(WM, XM, ACC, 0, 0, 0);  \
        ACC = __builtin_amdgcn_mfma_f32_16x16x32_bf16(WH, XL, ACC, 0, 0, 0);  \
        ACC = __builtin_amdgcn_mfma_f32_16x16x32_bf16(WL, XH, ACC, 0, 0, 0);
        PROD(a00, w0h, w0m, w0l, x0h, x0m, x0l)
        PROD(a01, w0h, w0m, w0l, x1h, x1m, x1l)
        PROD(a10, w1h, w1m, w1l, x0h, x0m, x0l)
        PROD(a11, w1h, w1m, w1l, x1h, x1m, x1l)
#undef PROD
    }
#define EPI(ACC, TO, TN)                                                      \
    {                                                                         \
        const int ob = ow + (TO) * 16 + l4 * 4;                               \
        const int n  = nw + (TN) * 16 + l15;                                  \
        const float rn = rnv[b * 4096 + n];                                   \
        if (ob < 256) {                                                       \
            out[((size_t)(b * 256 + ob + 0)) * 4096 + n] = ACC[0] * rn;       \
            out[((size_t)(b * 256 + ob + 1)) * 4096 + n] = ACC[1] * rn;       \
            out[((size_t)(b * 256 + ob + 2)) * 4096 + n] = ACC[2] * rn;       \
            out[((size_t)(b * 256 + ob + 3)) * 4096 + n] = ACC[3] * rn;       \
        } else {                                                              \
            float4 v = make_float4(ACC[0] * rn, ACC[1] * rn,                  \
                                   ACC[2] * rn, ACC[3] * rn);                 \
            *(float4*)&q[((size_t)(b * 4096 + n)) * 256 + (ob - 256)] = v;    \
        }                                                                     \
    }
    EPI(a00, 0, 0) EPI(a01, 0, 1) EPI(a10, 1, 0) EPI(a11, 1, 1)
#undef EPI
}

// ---- Kernel D: out = relu(P(out) + bias + max_k Q[nn]) in place ----
__global__ __launch_bounds__(256) void gather_kernel(const float* __restrict__ q,
                                                     const int* __restrict__ nn,
                                                     const float* __restrict__ bias,
                                                     float* __restrict__ out) {
    __shared__ int idx[32][9];
    const int b = blockIdx.y, n0 = blockIdx.x * 32;
    const int tid = threadIdx.x;
    for (int t = tid; t < 288; t += 256) {
        int pt = t / 9, k = t - pt * 9;
        idx[pt][k] = nn[(b * 4096 + n0 + pt) * 9 + k];
    }
    __syncthreads();
    const float bv = bias[tid];
    const size_t orow = ((size_t)(b * 256 + tid)) * 4096 + n0;
    float pvals[32];
#pragma unroll
    for (int u = 0; u < 8; ++u)
        *(float4*)&pvals[u * 4] = *(const float4*)&out[orow + u * 4];
    float val[32];
#pragma unroll
    for (int pt = 0; pt < 32; ++pt) {
        float m = -FLT_MAX;
#pragma unroll
        for (int k = 0; k < 9; ++k) {
            int j = idx[pt][k] & 4095;
            m = fmaxf(m, q[((size_t)(b * 4096 + j)) * 256 + tid]);
        }
        float vv = pvals[pt] + bv + m;
        val[pt] = vv > 0.f ? vv : 0.f;
    }
#pragma unroll
    for (int u = 0; u < 8; ++u) {
        float4 v = make_float4(val[u * 4], val[u * 4 + 1], val[u * 4 + 2], val[u * 4 + 3]);
        *(float4*)&out[orow + u * 4] = v;
    }
}

extern "C" void kernel_launch(void* const* d_in, const int* in_sizes, int n_in,
                              void* d_out, int out_size, void* d_ws, size_t ws_size,
                              hipStream_t stream) {
    const float* x    = (const float*)d_in[0];
    const float* w    = (const float*)d_in[1];
    const float* bias = (const float*)d_in[2];
    float* ws = (float*)d_ws;
    float* sq = ws + OFF_SQ;
    float* rn = ws + OFF_RN;
    unsigned short* wh = (unsigned short*)(ws + OFF_WP);
    unsigned short* wm = wh + 65536;
    unsigned short* wl = wm + 65536;
    unsigned short* xh = (unsigned short*)(ws + OFF_A);
    unsigned short* xm = xh + (size_t)CB * CN * CC;
    unsigned short* xl = xm + (size_t)CB * CN * CC;
    u32*   pk = (u32*)(ws + OFF_PK);
    float* q  = ws + OFF_PK;                    // overlays PK (merge precedes pq)
    int*   nn = (int*)(ws + OFF_NN);
    float* out = (float*)d_out;

    prep_kernel  <<<dim3(64, 2),     256, 0, stream>>>(x, sq, rn, xh, xm, xl);
    wprep_kernel <<<dim3(256),       256, 0, stream>>>(w, wh, wm, wl);
    knn_kernel   <<<dim3(16, 64, 2), 256, 0, stream>>>(xh, xm, xl, sq, pk);
    merge_kernel <<<dim3(64),        256, 0, stream>>>(pk, nn);
    pq_kernel    <<<dim3(64, 8, 2),  256, 0, stream>>>(xh, xm, xl, wh, wm, wl, rn, q, out);
    gather_kernel<<<dim3(128, 2),    256, 0, stream>>>(q, nn, bias, out);
}

// Round 19
// 158.126 us; speedup vs baseline: 1.9623x; 1.0020x over previous
//
#include <hip/hip_runtime.h>
#include <float.h>

// Problem constants: x (2,128,64,64) fp32, w (256,256) fp32, b (256,) fp32
// out (2,256,64,64) fp32. K=9 nearest neighbors on normalized features.
constexpr int CB = 2;       // batch
constexpr int CC = 128;     // channels
constexpr int CN = 4096;    // points (64*64)
constexpr int NSPLIT = 16;  // knn col-splits

typedef unsigned long long u64;
typedef unsigned int u32;

// ---- workspace layout (float offsets), total ~15.4 MB ----
// Lifetimes: x-planes (prep -> knn,pq), W-planes (wprep -> pq),
// PK (knn -> merge), Q (pq -> gather) OVERLAYS PK (merge precedes pq).
constexpr size_t OFF_SQ = 0;                         // [B][N] sum(xn^2)        8192 f
constexpr size_t OFF_RN = 8192;                      // [B][N] norm             8192 f
constexpr size_t OFF_WP = 16384;                     // W planes 3x65536 ushort 98304 f
constexpr size_t OFF_A  = 114688;                    // x planes 3x1048576 ushort = 1572864 f
constexpr size_t OFF_PK = OFF_A + 1572864;           // PK 1572864 u32 | Q 2097152 f (overlay)
constexpr size_t OFF_NN = OFF_PK + 2097152;          // [B][N][9] int           73728

typedef __attribute__((ext_vector_type(8))) short bf16x8;
typedef __attribute__((ext_vector_type(4))) float f32x4;

__device__ __forceinline__ unsigned short f2bf(float f) {
    u32 u = __float_as_uint(f);
    u32 r = (u + 0x7FFFu + ((u >> 16) & 1u)) >> 16;   // round-nearest-even
    return (unsigned short)r;
}
__device__ __forceinline__ float bf2f(unsigned short h) {
    return __uint_as_float(((u32)h) << 16);
}

// ---- u64-key top-9 machinery (r14/r15-proven) ----
// Key = mono(score)<<12 | (4095-j): larger key == better under the EXACT
// jax.lax.top_k order (score desc, index asc). Keys unique (j unique).
__device__ __forceinline__ u32 mono32(float v) {
    u32 u = __float_as_uint(v);
    u32 m = (u32)((int)u >> 31);
    return u ^ (m | 0x80000000u);
}
__device__ __forceinline__ u64 make_key(float v, int jg) {
    return ((u64)mono32(v) << 12) | (u32)(4095 - jg);
}
// sk sorted DESCENDING (sk[8]=min); unconditional bubble pass.
__device__ __forceinline__ void key_insert(u64 (&sk)[9], u64 key) {
    u64 t = key;
#pragma unroll
    for (int k = 0; k < 9; ++k) {
        const bool gt = t > sk[k];
        const u64 hi = gt ? t : sk[k];
        t = gt ? sk[k] : t;
        sk[k] = hi;
    }
}
__device__ __forceinline__ void key_init(u64 (&sk)[9]) {
#pragma unroll
    for (int k = 0; k < 9; ++k) sk[k] = (u64)(8 - k);   // descending sentinels
}

// ---- Kernel A: normalize + sq + rn + bf16x3 x-planes (fragment-major) ----
// plane[b][g=n>>4][q=c>>3][r=n&15][e=c&7]: frag load = contiguous 1KiB/wave.
__global__ __launch_bounds__(256) void prep_kernel(const float* __restrict__ x,
                                                   float* __restrict__ sqv,
                                                   float* __restrict__ rnv,
                                                   unsigned short* __restrict__ xh,
                                                   unsigned short* __restrict__ xm,
                                                   unsigned short* __restrict__ xl) {
    __shared__ float XT[128][65];
    __shared__ float red[4][64];
    __shared__ float invl[64];
    const int b = blockIdx.y, n0 = blockIdx.x * 64;
    const int tid = threadIdx.x;
    const int nl = tid & 63, c0 = tid >> 6;
#pragma unroll 4
    for (int cc = 0; cc < 32; ++cc) {
        int c = cc * 4 + c0;
        XT[c][nl] = x[((size_t)(b * 128 + c)) * 4096 + n0 + nl];
    }
    __syncthreads();
    {
        float acc = 0.f;
#pragma unroll 4
        for (int cc = 0; cc < 32; ++cc) { float v = XT[c0 * 32 + cc][nl]; acc += v * v; }
        red[c0][nl] = acc;
    }
    __syncthreads();
    if (tid < 64) {
        float ss = red[0][tid] + red[1][tid] + red[2][tid] + red[3][tid] + 1e-12f;
        float sr = sqrtf(ss);
        invl[tid] = 1.0f / sr;
        rnv[b * 4096 + n0 + tid] = sr;
    }
    __syncthreads();
    {
        float acc = 0.f;
        float iv = invl[nl];
#pragma unroll 4
        for (int cc = 0; cc < 32; ++cc) {
            int c = cc * 4 + c0;
            float v = XT[c][nl] * iv;
            XT[c][nl] = v;
            acc += v * v;
        }
        red[c0][nl] = acc;
    }
    __syncthreads();
    if (tid < 64) {
        sqv[b * 4096 + n0 + tid] = red[0][tid] + red[1][tid] + red[2][tid] + red[3][tid];
    }
    __syncthreads();
    {
        const int n = tid & 63, cq = tid >> 6;
        unsigned short hs[32], ms[32], ls[32];
#pragma unroll
        for (int cc = 0; cc < 32; ++cc) {
            float v = XT[cq * 32 + cc][n];
            unsigned short h = f2bf(v);  float hf = bf2f(h);
            float r1 = v - hf;
            unsigned short m = f2bf(r1); float mf = bf2f(m);
            unsigned short l = f2bf(r1 - mf);
            hs[cc] = h; ms[cc] = m; ls[cc] = l;
        }
        const int g = (n0 >> 4) + (n >> 4), r = n & 15;
        const size_t gb = ((size_t)(b * 256 + g)) * 2048 + r * 8;
#pragma unroll
        for (int u = 0; u < 4; ++u) {
            const size_t off = gb + (size_t)(cq * 4 + u) * 128;
            *(float4*)&xh[off] = *(const float4*)&hs[u * 8];
            *(float4*)&xm[off] = *(const float4*)&ms[u * 8];
            *(float4*)&xl[off] = *(const float4*)&ls[u * 8];
        }
    }
}

// ---- Kernel W: packed WT = (W1-W2 | W2)^T, bf16x3 split, fragment-major ----
// wplane[g=o'>>4][q=c>>3][r=o'&15][e=c&7]
__global__ __launch_bounds__(256) void wprep_kernel(const float* __restrict__ w,
                                                    unsigned short* __restrict__ wh,
                                                    unsigned short* __restrict__ wm,
                                                    unsigned short* __restrict__ wl) {
    int id = blockIdx.x * 256 + threadIdx.x;   // 65536 = 128*512
    int c = id >> 9, o = id & 511;
    float v;
    if (o < 256) v = w[o * 256 + c] - w[o * 256 + 128 + c];
    else         v = w[(o - 256) * 256 + 128 + c];
    unsigned short h = f2bf(v);  float hf = bf2f(h);
    float r1 = v - hf;
    unsigned short m = f2bf(r1); float mf = bf2f(m);
    unsigned short l = f2bf(r1 - mf);
    const size_t off = (size_t)(o >> 4) * 2048 + (c >> 3) * 128 + (o & 15) * 8 + (c & 7);
    wh[off] = h; wm[off] = m; wl[off] = l;
}

// ---- Kernel B v19: MFMA bf16x3 Gram + I-FRAG HOISTING ----
// = v18 with the 12 I-fragments (3 planes x 4 K-chunks) hoisted out of the
// tile loop: they are loop-invariant (same i-rows all 4 tiles). Removes 36 of
// 240 loads/wave and shortens each tile's dependent chain to J-loads only.
// VGPR: 64 -> ~112 (+16 AGPR acc = at the 4-wave cliff). r17's spill
// signature (VGPR collapse + FETCH/WRITE explosion) is the abort detector.
// (256,4): r15/r18-proven (r17: (256,8) starved the file -> 1GB scratch).
__global__ __launch_bounds__(256, 4) void knn_kernel(const unsigned short* __restrict__ xh,
                                                     const unsigned short* __restrict__ xm,
                                                     const unsigned short* __restrict__ xl,
                                                     const float* __restrict__ sqv,
                                                     u32* __restrict__ pk) {
    __shared__ u64 MK[2304];                   // 18,432 B: [256][9] keys

    const int b  = blockIdx.z;
    const int i0 = blockIdx.y * 64;
    const int js = blockIdx.x;                 // 0..15, cols js*256 .. +255
    const int tid = threadIdx.x;
    const int lane = tid & 63, w = tid >> 6;
    const int l15 = lane & 15, l4 = lane >> 4;

    const size_t ib0 = ((size_t)(b * 256 + (i0 >> 4) + w)) * 2048;
    u64 sk[9];
    key_init(sk);

    // hoisted I-frags: loop-invariant across the 4 j-tiles (fully unrolled ->
    // static indexing, stays in registers per rule #20)
    bf16x8 ihf[4], imf[4], ilf[4];
#pragma unroll
    for (int ch = 0; ch < 4; ++ch) {
        const int koff = (ch * 4 + l4) * 128 + l15 * 8;
        ihf[ch] = *(const bf16x8*)(xh + ib0 + koff);
        imf[ch] = *(const bf16x8*)(xm + ib0 + koff);
        ilf[ch] = *(const bf16x8*)(xl + ib0 + koff);
    }

    for (int tt = 0; tt < 4; ++tt) {
        const int t = (tt + w) & 3;            // stagger: waves desynchronized
        const int jt = js * 256 + t * 64;
        const size_t jb0 = ((size_t)(b * 256 + (jt >> 4))) * 2048;  // + Y*2048
        f32x4 a0 = {0.f, 0.f, 0.f, 0.f}, a1 = a0, a2 = a0, a3 = a0;

#pragma unroll
        for (int ch = 0; ch < 4; ++ch) {       // K chunks of 32; no barriers
            const int koff = (ch * 4 + l4) * 128 + l15 * 8;   // shorts, 1KiB/wave
            const bf16x8 ih = ihf[ch];
            const bf16x8 im = imf[ch];
            const bf16x8 il = ilf[ch];
#define DO_Y(ACC, Y)                                                          \
            {                                                                 \
                const bf16x8 jh = *(const bf16x8*)(xh + jb0 + (Y) * 2048 + koff); \
                const bf16x8 jm = *(const bf16x8*)(xm + jb0 + (Y) * 2048 + koff); \
                const bf16x8 jl = *(const bf16x8*)(xl + jb0 + (Y) * 2048 + koff); \
                ACC = __builtin_amdgcn_mfma_f32_16x16x32_bf16(jh, ih, ACC, 0, 0, 0); \
                ACC = __builtin_amdgcn_mfma_f32_16x16x32_bf16(jh, im, ACC, 0, 0, 0); \
                ACC = __builtin_amdgcn_mfma_f32_16x16x32_bf16(jm, ih, ACC, 0, 0, 0); \
                ACC = __builtin_amdgcn_mfma_f32_16x16x32_bf16(jm, im, ACC, 0, 0, 0); \
                ACC = __builtin_amdgcn_mfma_f32_16x16x32_bf16(jh, il, ACC, 0, 0, 0); \
                ACC = __builtin_amdgcn_mfma_f32_16x16x32_bf16(jl, ih, ACC, 0, 0, 0); \
            }
            DO_Y(a0, 0) DO_Y(a1, 1) DO_Y(a2, 2) DO_Y(a3, 3)
#undef DO_Y
        }
#define SCAN_Y(ACC, Y)                                                        \
        {                                                                     \
            const int jb4 = jt + (Y) * 16 + l4 * 4;                           \
            const float4 sq4 = *(const float4*)&sqv[b * 4096 + jb4];          \
            key_insert(sk, make_key(fmaf(2.0f, ACC[0], -sq4.x), jb4 + 0));    \
            key_insert(sk, make_key(fmaf(2.0f, ACC[1], -sq4.y), jb4 + 1));    \
            key_insert(sk, make_key(fmaf(2.0f, ACC[2], -sq4.z), jb4 + 2));    \
            key_insert(sk, make_key(fmaf(2.0f, ACC[3], -sq4.w), jb4 + 3));    \
        }
        SCAN_Y(a0, 0) SCAN_Y(a1, 1) SCAN_Y(a2, 2) SCAN_Y(a3, 3)
#undef SCAN_Y
    }
    // merge: i-row (w*16 + l15) has 4 disjoint-j lists at lanes {l15 + 16*l4}
#pragma unroll
    for (int k = 0; k < 9; ++k) MK[tid * 9 + k] = sk[k];
    __syncthreads();
    if (tid < 64) {                            // i = i0 + tid
        u64 mk[9];
        key_init(mk);
        const int wsrc = tid >> 4, r = tid & 15;
        for (int q2 = 0; q2 < 4; ++q2) {
            const int src = wsrc * 64 + q2 * 16 + r;
            for (int k = 0; k < 9; ++k) key_insert(mk, MK[src * 9 + k]);
        }
        // compress: 9 mono-scores + 9 x 8-bit local-j in 3 words (exact)
        u32 ow[12];
        u32 iw0 = 0, iw1 = 0, iw2 = 0;
#pragma unroll
        for (int k = 0; k < 9; ++k) {
            ow[k] = (u32)(mk[k] >> 12);
            u32 lj = (u32)((4095 - (int)(mk[k] & 4095)) - js * 256) & 255u;
            if (k < 4)      iw0 |= lj << (k * 8);
            else if (k < 8) iw1 |= lj << ((k - 4) * 8);
            else            iw2 |= lj;
        }
        ow[9] = iw0; ow[10] = iw1; ow[11] = iw2;
        const size_t base = ((size_t)(b * 4096 + i0 + tid) * NSPLIT + js) * 12;
        *(uint4*)&pk[base]     = *(const uint4*)&ow[0];
        *(uint4*)&pk[base + 4] = *(const uint4*)&ow[4];
        *(uint4*)&pk[base + 8] = *(const uint4*)&ow[8];
    }
}

// ---- Kernel M: merge 16 split-lists -> final 9 indices; 2 threads/row ----
__global__ __launch_bounds__(256) void merge_kernel(const u32* __restrict__ pk,
                                                    int* __restrict__ nn) {
    const int gt = blockIdx.x * 256 + threadIdx.x;   // 16384 threads
    const int row = gt >> 1, half = gt & 1;
    u64 mk[9];
    key_init(mk);
    for (int s = half * 8; s < half * 8 + 8; ++s) {
        const u32* p = pk + ((size_t)row * NSPLIT + s) * 12;
        u32 ow[12];
        *(uint4*)&ow[0] = *(const uint4*)&p[0];
        *(uint4*)&ow[4] = *(const uint4*)&p[4];
        *(uint4*)&ow[8] = *(const uint4*)&p[8];
        const u32 iw[3] = {ow[9], ow[10], ow[11]};
#pragma unroll
        for (int k = 0; k < 9; ++k) {
            const int lj = (int)((iw[k >> 2] >> ((k & 3) * 8)) & 255u);
            const int jg = s * 256 + lj;
            key_insert(mk, ((u64)ow[k] << 12) | (u32)(4095 - jg));
        }
    }
    // exchange partner's 9 keys (adjacent lane) and fold in
    u64 tmp[9];
#pragma unroll
    for (int k = 0; k < 9; ++k) tmp[k] = __shfl_xor(mk[k], 1);
#pragma unroll
    for (int k = 0; k < 9; ++k) key_insert(mk, tmp[k]);
    if (half == 0) {
#pragma unroll
        for (int k = 0; k < 9; ++k) nn[row * 9 + k] = 4095 - (int)(mk[k] & 4095);
    }
}

// ---- Kernel C v2: P/Q GEMM via MFMA bf16x3 (barrier-free, no LDS) ----
// mfma(W, X): D row = W-row = o' ((lane>>4)*4+reg), col = X-row = n (lane&15)
// [orientation HW-verified r10-r15]. value = acc * rn[n]. P (o'<256) ->
// out[b][o'][n] scalar stores; Q (o'>=256) -> q[b][n][o'-256] float4.
__global__ __launch_bounds__(256, 4) void pq_kernel(const unsigned short* __restrict__ xh,
                                                    const unsigned short* __restrict__ xm,
                                                    const unsigned short* __restrict__ xl,
                                                    const unsigned short* __restrict__ wh,
                                                    const unsigned short* __restrict__ wm,
                                                    const unsigned short* __restrict__ wl,
                                                    const float* __restrict__ rnv,
                                                    float* __restrict__ q,
                                                    float* __restrict__ out) {
    const int b  = blockIdx.z;
    const int n0 = blockIdx.x * 64;
    const int o0 = blockIdx.y * 64;
    const int tid = threadIdx.x;
    const int lane = tid & 63, w = tid >> 6;
    const int l15 = lane & 15, l4 = lane >> 4;
    const int nw = n0 + (w & 1) * 32;
    const int ow = o0 + (w >> 1) * 32;

    const size_t xg = ((size_t)(b * 256 + (nw >> 4))) * 2048;   // + tn*2048
    const size_t wg = ((size_t)(ow >> 4)) * 2048;               // + to*2048

    f32x4 a00 = {0.f, 0.f, 0.f, 0.f}, a01 = a00, a10 = a00, a11 = a00;  // [to][tn]

#pragma unroll
    for (int ch = 0; ch < 4; ++ch) {
        const int koff = (ch * 4 + l4) * 128 + l15 * 8;
        const bf16x8 x0h = *(const bf16x8*)(xh + xg + koff);
        const bf16x8 x0m = *(const bf16x8*)(xm + xg + koff);
        const bf16x8 x0l = *(const bf16x8*)(xl + xg + koff);
        const bf16x8 x1h = *(const bf16x8*)(xh + xg + 2048 + koff);
        const bf16x8 x1m = *(const bf16x8*)(xm + xg + 2048 + koff);
        const bf16x8 x1l = *(const bf16x8*)(xl + xg + 2048 + koff);
        const bf16x8 w0h = *(const bf16x8*)(wh + wg + koff);
        const bf16x8 w0m = *(const bf16x8*)(wm + wg + koff);
        const bf16x8 w0l = *(const bf16x8*)(wl + wg + koff);
        const bf16x8 w1h = *(const bf16x8*)(wh + wg + 2048 + koff);
        const bf16x8 w1m = *(const bf16x8*)(wm + wg + 2048 + koff);
        const bf16x8 w1l = *(const bf16x8*)(wl + wg + 2048 + koff);
#define PROD(ACC, WH, WM, WL, XH, XM, XL)                                     \
        ACC = __builtin_amdgcn_mfma_f32_16x16x32_bf16(WH, XH, ACC, 0, 0, 0);  \
        ACC = __builtin_amdgcn_mfma_f32_16x16x32_bf16(WH, XM, ACC, 0, 0, 0);  \
        ACC = __builtin_amdgcn_mfma_f32_16x16x32_bf16(WM, XH, ACC, 0, 0, 0);  \
        ACC = __builtin_amdgcn_mfma_f32_16x16x32_bf16(WM, XM, ACC, 0, 0, 0);  \
        ACC = __builtin_amdgcn_mfma_f32_16x16x32_bf16(WH, XL, ACC, 0, 0, 0);  \
        ACC = __builtin_amdgcn_mfma_f32_16x16x32_bf16(WL, XH, ACC, 0, 0, 0);
        PROD(a00, w0h, w0m, w0l, x0h, x0m, x0l)
        PROD(a01, w0h, w0m, w0l, x1h, x1m, x1l)
        PROD(a10, w1h, w1m, w1l, x0h, x0m, x0l)
        PROD(a11, w1h, w1m, w1l, x1h, x1m, x1l)
#undef PROD
    }
#define EPI(ACC, TO, TN)                                                      \
    {                                                                         \
        const int ob = ow + (TO) * 16 + l4 * 4;                               \
        const int n  = nw + (TN) * 16 + l15;                                  \
        const float rn = rnv[b * 4096 + n];                                   \
        if (ob < 256) {                                                       \
            out[((size_t)(b * 256 + ob + 0)) * 4096 + n] = ACC[0] * rn;       \
            out[((size_t)(b * 256 + ob + 1)) * 4096 + n] = ACC[1] * rn;       \
            out[((size_t)(b * 256 + ob + 2)) * 4096 + n] = ACC[2] * rn;       \
            out[((size_t)(b * 256 + ob + 3)) * 4096 + n] = ACC[3] * rn;       \
        } else {                                                              \
            float4 v = make_float4(ACC[0] * rn, ACC[1] * rn,                  \
                                   ACC[2] * rn, ACC[3] * rn);                 \
            *(float4*)&q[((size_t)(b * 4096 + n)) * 256 + (ob - 256)] = v;    \
        }                                                                     \
    }
    EPI(a00, 0, 0) EPI(a01, 0, 1) EPI(a10, 1, 0) EPI(a11, 1, 1)
#undef EPI
}

// ---- Kernel D: out = relu(P(out) + bias + max_k Q[nn]) in place ----
__global__ __launch_bounds__(256) void gather_kernel(const float* __restrict__ q,
                                                     const int* __restrict__ nn,
                                                     const float* __restrict__ bias,
                                                     float* __restrict__ out) {
    __shared__ int idx[32][9];
    const int b = blockIdx.y, n0 = blockIdx.x * 32;
    const int tid = threadIdx.x;
    for (int t = tid; t < 288; t += 256) {
        int pt = t / 9, k = t - pt * 9;
        idx[pt][k] = nn[(b * 4096 + n0 + pt) * 9 + k];
    }
    __syncthreads();
    const float bv = bias[tid];
    const size_t orow = ((size_t)(b * 256 + tid)) * 4096 + n0;
    float pvals[32];
#pragma unroll
    for (int u = 0; u < 8; ++u)
        *(float4*)&pvals[u * 4] = *(const float4*)&out[orow + u * 4];
    float val[32];
#pragma unroll
    for (int pt = 0; pt < 32; ++pt) {
        float m = -FLT_MAX;
#pragma unroll
        for (int k = 0; k < 9; ++k) {
            int j = idx[pt][k] & 4095;
            m = fmaxf(m, q[((size_t)(b * 4096 + j)) * 256 + tid]);
        }
        float vv = pvals[pt] + bv + m;
        val[pt] = vv > 0.f ? vv : 0.f;
    }
#pragma unroll
    for (int u = 0; u < 8; ++u) {
        float4 v = make_float4(val[u * 4], val[u * 4 + 1], val[u * 4 + 2], val[u * 4 + 3]);
        *(float4*)&out[orow + u * 4] = v;
    }
}

extern "C" void kernel_launch(void* const* d_in, const int* in_sizes, int n_in,
                              void* d_out, int out_size, void* d_ws, size_t ws_size,
                              hipStream_t stream) {
    const float* x    = (const float*)d_in[0];
    const float* w    = (const float*)d_in[1];
    const float* bias = (const float*)d_in[2];
    float* ws = (float*)d_ws;
    float* sq = ws + OFF_SQ;
    float* rn = ws + OFF_RN;
    unsigned short* wh = (unsigned short*)(ws + OFF_WP);
    unsigned short* wm = wh + 65536;
    unsigned short* wl = wm + 65536;
    unsigned short* xh = (unsigned short*)(ws + OFF_A);
    unsigned short* xm = xh + (size_t)CB * CN * CC;
    unsigned short* xl = xm + (size_t)CB * CN * CC;
    u32*   pk = (u32*)(ws + OFF_PK);
    float* q  = ws + OFF_PK;                    // overlays PK (merge precedes pq)
    int*   nn = (int*)(ws + OFF_NN);
    float* out = (float*)d_out;

    prep_kernel  <<<dim3(64, 2),     256, 0, stream>>>(x, sq, rn, xh, xm, xl);
    wprep_kernel <<<dim3(256),       256, 0, stream>>>(w, wh, wm, wl);
    knn_kernel   <<<dim3(16, 64, 2), 256, 0, stream>>>(xh, xm, xl, sq, pk);
    merge_kernel <<<dim3(64),        256, 0, stream>>>(pk, nn);
    pq_kernel    <<<dim3(64, 8, 2),  256, 0, stream>>>(xh, xm, xl, wh, wm, wl, rn, q, out);
    gather_kernel<<<dim3(128, 2),    256, 0, stream>>>(q, nn, bias, out);
}

// Round 20
// 156.550 us; speedup vs baseline: 1.9821x; 1.0101x over previous
//
#include <hip/hip_runtime.h>
#include <float.h>

// Problem constants: x (2,128,64,64) fp32, w (256,256) fp32, b (256,) fp32
// out (2,256,64,64) fp32. K=9 nearest neighbors on normalized features.
constexpr int CB = 2;       // batch
constexpr int CC = 128;     // channels
constexpr int CN = 4096;    // points (64*64)
constexpr int NSPLIT = 16;  // knn col-splits

typedef unsigned long long u64;
typedef unsigned int u32;

// ---- workspace layout (float offsets), total ~15.4 MB ----
// Lifetimes: x-planes (prep -> knn,pq), W-planes (wprep -> pq),
// PK (knn -> merge), Q (pq -> gather) OVERLAYS PK (merge precedes pq).
constexpr size_t OFF_SQ = 0;                         // [B][N] sum(xn^2)        8192 f
constexpr size_t OFF_RN = 8192;                      // [B][N] norm             8192 f
constexpr size_t OFF_WP = 16384;                     // W planes 3x65536 ushort 98304 f
constexpr size_t OFF_A  = 114688;                    // x planes 3x1048576 ushort = 1572864 f
constexpr size_t OFF_PK = OFF_A + 1572864;           // PK 1572864 u32 | Q 2097152 f (overlay)
constexpr size_t OFF_NN = OFF_PK + 2097152;          // [B][N][9] int           73728

typedef __attribute__((ext_vector_type(8))) short bf16x8;
typedef __attribute__((ext_vector_type(4))) float f32x4;

__device__ __forceinline__ unsigned short f2bf(float f) {
    u32 u = __float_as_uint(f);
    u32 r = (u + 0x7FFFu + ((u >> 16) & 1u)) >> 16;   // round-nearest-even
    return (unsigned short)r;
}
__device__ __forceinline__ float bf2f(unsigned short h) {
    return __uint_as_float(((u32)h) << 16);
}

// ---- u64-key top-9 machinery (r14/r15-proven) ----
// Key = mono(score)<<12 | (4095-j): larger key == better under the EXACT
// jax.lax.top_k order (score desc, index asc). Keys unique (j unique).
__device__ __forceinline__ u32 mono32(float v) {
    u32 u = __float_as_uint(v);
    u32 m = (u32)((int)u >> 31);
    return u ^ (m | 0x80000000u);
}
__device__ __forceinline__ u64 make_key(float v, int jg) {
    return ((u64)mono32(v) << 12) | (u32)(4095 - jg);
}
// sk sorted DESCENDING (sk[8]=min); unconditional bubble pass.
__device__ __forceinline__ void key_insert(u64 (&sk)[9], u64 key) {
    u64 t = key;
#pragma unroll
    for (int k = 0; k < 9; ++k) {
        const bool gt = t > sk[k];
        const u64 hi = gt ? t : sk[k];
        t = gt ? sk[k] : t;
        sk[k] = hi;
    }
}
__device__ __forceinline__ void key_init(u64 (&sk)[9]) {
#pragma unroll
    for (int k = 0; k < 9; ++k) sk[k] = (u64)(8 - k);   // descending sentinels
}

// ---- Kernel A: normalize + sq + rn + bf16x3 x-planes (fragment-major) ----
// plane[b][g=n>>4][q=c>>3][r=n&15][e=c&7]: frag load = contiguous 1KiB/wave.
__global__ __launch_bounds__(256) void prep_kernel(const float* __restrict__ x,
                                                   float* __restrict__ sqv,
                                                   float* __restrict__ rnv,
                                                   unsigned short* __restrict__ xh,
                                                   unsigned short* __restrict__ xm,
                                                   unsigned short* __restrict__ xl) {
    __shared__ float XT[128][65];
    __shared__ float red[4][64];
    __shared__ float invl[64];
    const int b = blockIdx.y, n0 = blockIdx.x * 64;
    const int tid = threadIdx.x;
    const int nl = tid & 63, c0 = tid >> 6;
#pragma unroll 4
    for (int cc = 0; cc < 32; ++cc) {
        int c = cc * 4 + c0;
        XT[c][nl] = x[((size_t)(b * 128 + c)) * 4096 + n0 + nl];
    }
    __syncthreads();
    {
        float acc = 0.f;
#pragma unroll 4
        for (int cc = 0; cc < 32; ++cc) { float v = XT[c0 * 32 + cc][nl]; acc += v * v; }
        red[c0][nl] = acc;
    }
    __syncthreads();
    if (tid < 64) {
        float ss = red[0][tid] + red[1][tid] + red[2][tid] + red[3][tid] + 1e-12f;
        float sr = sqrtf(ss);
        invl[tid] = 1.0f / sr;
        rnv[b * 4096 + n0 + tid] = sr;
    }
    __syncthreads();
    {
        float acc = 0.f;
        float iv = invl[nl];
#pragma unroll 4
        for (int cc = 0; cc < 32; ++cc) {
            int c = cc * 4 + c0;
            float v = XT[c][nl] * iv;
            XT[c][nl] = v;
            acc += v * v;
        }
        red[c0][nl] = acc;
    }
    __syncthreads();
    if (tid < 64) {
        sqv[b * 4096 + n0 + tid] = red[0][tid] + red[1][tid] + red[2][tid] + red[3][tid];
    }
    __syncthreads();
    {
        const int n = tid & 63, cq = tid >> 6;
        unsigned short hs[32], ms[32], ls[32];
#pragma unroll
        for (int cc = 0; cc < 32; ++cc) {
            float v = XT[cq * 32 + cc][n];
            unsigned short h = f2bf(v);  float hf = bf2f(h);
            float r1 = v - hf;
            unsigned short m = f2bf(r1); float mf = bf2f(m);
            unsigned short l = f2bf(r1 - mf);
            hs[cc] = h; ms[cc] = m; ls[cc] = l;
        }
        const int g = (n0 >> 4) + (n >> 4), r = n & 15;
        const size_t gb = ((size_t)(b * 256 + g)) * 2048 + r * 8;
#pragma unroll
        for (int u = 0; u < 4; ++u) {
            const size_t off = gb + (size_t)(cq * 4 + u) * 128;
            *(float4*)&xh[off] = *(const float4*)&hs[u * 8];
            *(float4*)&xm[off] = *(const float4*)&ms[u * 8];
            *(float4*)&xl[off] = *(const float4*)&ls[u * 8];
        }
    }
}

// ---- Kernel W: packed WT = (W1-W2 | W2)^T, bf16x3 split, fragment-major ----
// wplane[g=o'>>4][q=c>>3][r=o'&15][e=c&7]
__global__ __launch_bounds__(256) void wprep_kernel(const float* __restrict__ w,
                                                    unsigned short* __restrict__ wh,
                                                    unsigned short* __restrict__ wm,
                                                    unsigned short* __restrict__ wl) {
    int id = blockIdx.x * 256 + threadIdx.x;   // 65536 = 128*512
    int c = id >> 9, o = id & 511;
    float v;
    if (o < 256) v = w[o * 256 + c] - w[o * 256 + 128 + c];
    else         v = w[(o - 256) * 256 + 128 + c];
    unsigned short h = f2bf(v);  float hf = bf2f(h);
    float r1 = v - hf;
    unsigned short m = f2bf(r1); float mf = bf2f(m);
    unsigned short l = f2bf(r1 - mf);
    const size_t off = (size_t)(o >> 4) * 2048 + (c >> 3) * 128 + (o & 15) * 8 + (c & 7);
    wh[off] = h; wm[off] = m; wl[off] = l;
}

// ---- Kernel B v20: MFMA bf16x3 Gram + UNROLLED tile loop ----
// = v18/v19 with #pragma unroll on the 4-iteration tile loop: without it the
// compiler cannot move tile t+1's J-loads across the loop back-edge; each tile
// serially pays {48 J-loads -> 24 MFMA -> ~3200-inst scan}. Unrolled, the
// scheduler can issue next-tile loads under the current tile's scan chain
// (~6400 cyc >> ~500 cyc L2 latency) -> attacks the ~33us un-hidden stall.
// Abort detector (r17 signature): VGPR collapse + FETCH/WRITE explosion.
// (256,4): r15/r18-proven. Selection bit-identical (same ops, same order).
__global__ __launch_bounds__(256, 4) void knn_kernel(const unsigned short* __restrict__ xh,
                                                     const unsigned short* __restrict__ xm,
                                                     const unsigned short* __restrict__ xl,
                                                     const float* __restrict__ sqv,
                                                     u32* __restrict__ pk) {
    __shared__ u64 MK[2304];                   // 18,432 B: [256][9] keys

    const int b  = blockIdx.z;
    const int i0 = blockIdx.y * 64;
    const int js = blockIdx.x;                 // 0..15, cols js*256 .. +255
    const int tid = threadIdx.x;
    const int lane = tid & 63, w = tid >> 6;
    const int l15 = lane & 15, l4 = lane >> 4;

    const size_t ib0 = ((size_t)(b * 256 + (i0 >> 4) + w)) * 2048;
    u64 sk[9];
    key_init(sk);

#pragma unroll
    for (int tt = 0; tt < 4; ++tt) {
        const int t = (tt + w) & 3;            // stagger: waves desynchronized
        const int jt = js * 256 + t * 64;
        const size_t jb0 = ((size_t)(b * 256 + (jt >> 4))) * 2048;  // + Y*2048
        f32x4 a0 = {0.f, 0.f, 0.f, 0.f}, a1 = a0, a2 = a0, a3 = a0;

#pragma unroll
        for (int ch = 0; ch < 4; ++ch) {       // K chunks of 32; no barriers
            const int koff = (ch * 4 + l4) * 128 + l15 * 8;   // shorts, 1KiB/wave
            const bf16x8 ih = *(const bf16x8*)(xh + ib0 + koff);
            const bf16x8 im = *(const bf16x8*)(xm + ib0 + koff);
            const bf16x8 il = *(const bf16x8*)(xl + ib0 + koff);
#define DO_Y(ACC, Y)                                                          \
            {                                                                 \
                const bf16x8 jh = *(const bf16x8*)(xh + jb0 + (Y) * 2048 + koff); \
                const bf16x8 jm = *(const bf16x8*)(xm + jb0 + (Y) * 2048 + koff); \
                const bf16x8 jl = *(const bf16x8*)(xl + jb0 + (Y) * 2048 + koff); \
                ACC = __builtin_amdgcn_mfma_f32_16x16x32_bf16(jh, ih, ACC, 0, 0, 0); \
                ACC = __builtin_amdgcn_mfma_f32_16x16x32_bf16(jh, im, ACC, 0, 0, 0); \
                ACC = __builtin_amdgcn_mfma_f32_16x16x32_bf16(jm, ih, ACC, 0, 0, 0); \
                ACC = __builtin_amdgcn_mfma_f32_16x16x32_bf16(jm, im, ACC, 0, 0, 0); \
                ACC = __builtin_amdgcn_mfma_f32_16x16x32_bf16(jh, il, ACC, 0, 0, 0); \
                ACC = __builtin_amdgcn_mfma_f32_16x16x32_bf16(jl, ih, ACC, 0, 0, 0); \
            }
            DO_Y(a0, 0) DO_Y(a1, 1) DO_Y(a2, 2) DO_Y(a3, 3)
#undef DO_Y
        }
#define SCAN_Y(ACC, Y)                                                        \
        {                                                                     \
            const int jb4 = jt + (Y) * 16 + l4 * 4;                           \
            const float4 sq4 = *(const float4*)&sqv[b * 4096 + jb4];          \
            key_insert(sk, make_key(fmaf(2.0f, ACC[0], -sq4.x), jb4 + 0));    \
            key_insert(sk, make_key(fmaf(2.0f, ACC[1], -sq4.y), jb4 + 1));    \
            key_insert(sk, make_key(fmaf(2.0f, ACC[2], -sq4.z), jb4 + 2));    \
            key_insert(sk, make_key(fmaf(2.0f, ACC[3], -sq4.w), jb4 + 3));    \
        }
        SCAN_Y(a0, 0) SCAN_Y(a1, 1) SCAN_Y(a2, 2) SCAN_Y(a3, 3)
#undef SCAN_Y
    }
    // merge: i-row (w*16 + l15) has 4 disjoint-j lists at lanes {l15 + 16*l4}
#pragma unroll
    for (int k = 0; k < 9; ++k) MK[tid * 9 + k] = sk[k];
    __syncthreads();
    if (tid < 64) {                            // i = i0 + tid
        u64 mk[9];
        key_init(mk);
        const int wsrc = tid >> 4, r = tid & 15;
        for (int q2 = 0; q2 < 4; ++q2) {
            const int src = wsrc * 64 + q2 * 16 + r;
            for (int k = 0; k < 9; ++k) key_insert(mk, MK[src * 9 + k]);
        }
        // compress: 9 mono-scores + 9 x 8-bit local-j in 3 words (exact)
        u32 ow[12];
        u32 iw0 = 0, iw1 = 0, iw2 = 0;
#pragma unroll
        for (int k = 0; k < 9; ++k) {
            ow[k] = (u32)(mk[k] >> 12);
            u32 lj = (u32)((4095 - (int)(mk[k] & 4095)) - js * 256) & 255u;
            if (k < 4)      iw0 |= lj << (k * 8);
            else if (k < 8) iw1 |= lj << ((k - 4) * 8);
            else            iw2 |= lj;
        }
        ow[9] = iw0; ow[10] = iw1; ow[11] = iw2;
        const size_t base = ((size_t)(b * 4096 + i0 + tid) * NSPLIT + js) * 12;
        *(uint4*)&pk[base]     = *(const uint4*)&ow[0];
        *(uint4*)&pk[base + 4] = *(const uint4*)&ow[4];
        *(uint4*)&pk[base + 8] = *(const uint4*)&ow[8];
    }
}

// ---- Kernel M: merge 16 split-lists -> final 9 indices; 2 threads/row ----
__global__ __launch_bounds__(256) void merge_kernel(const u32* __restrict__ pk,
                                                    int* __restrict__ nn) {
    const int gt = blockIdx.x * 256 + threadIdx.x;   // 16384 threads
    const int row = gt >> 1, half = gt & 1;
    u64 mk[9];
    key_init(mk);
    for (int s = half * 8; s < half * 8 + 8; ++s) {
        const u32* p = pk + ((size_t)row * NSPLIT + s) * 12;
        u32 ow[12];
        *(uint4*)&ow[0] = *(const uint4*)&p[0];
        *(uint4*)&ow[4] = *(const uint4*)&p[4];
        *(uint4*)&ow[8] = *(const uint4*)&p[8];
        const u32 iw[3] = {ow[9], ow[10], ow[11]};
#pragma unroll
        for (int k = 0; k < 9; ++k) {
            const int lj = (int)((iw[k >> 2] >> ((k & 3) * 8)) & 255u);
            const int jg = s * 256 + lj;
            key_insert(mk, ((u64)ow[k] << 12) | (u32)(4095 - jg));
        }
    }
    // exchange partner's 9 keys (adjacent lane) and fold in
    u64 tmp[9];
#pragma unroll
    for (int k = 0; k < 9; ++k) tmp[k] = __shfl_xor(mk[k], 1);
#pragma unroll
    for (int k = 0; k < 9; ++k) key_insert(mk, tmp[k]);
    if (half == 0) {
#pragma unroll
        for (int k = 0; k < 9; ++k) nn[row * 9 + k] = 4095 - (int)(mk[k] & 4095);
    }
}

// ---- Kernel C v2: P/Q GEMM via MFMA bf16x3 (barrier-free, no LDS) ----
// mfma(W, X): D row = W-row = o' ((lane>>4)*4+reg), col = X-row = n (lane&15)
// [orientation HW-verified r10-r15]. value = acc * rn[n]. P (o'<256) ->
// out[b][o'][n] scalar stores; Q (o'>=256) -> q[b][n][o'-256] float4.
__global__ __launch_bounds__(256, 4) void pq_kernel(const unsigned short* __restrict__ xh,
                                                    const unsigned short* __restrict__ xm,
                                                    const unsigned short* __restrict__ xl,
                                                    const unsigned short* __restrict__ wh,
                                                    const unsigned short* __restrict__ wm,
                                                    const unsigned short* __restrict__ wl,
                                                    const float* __restrict__ rnv,
                                                    float* __restrict__ q,
                                                    float* __restrict__ out) {
    const int b  = blockIdx.z;
    const int n0 = blockIdx.x * 64;
    const int o0 = blockIdx.y * 64;
    const int tid = threadIdx.x;
    const int lane = tid & 63, w = tid >> 6;
    const int l15 = lane & 15, l4 = lane >> 4;
    const int nw = n0 + (w & 1) * 32;
    const int ow = o0 + (w >> 1) * 32;

    const size_t xg = ((size_t)(b * 256 + (nw >> 4))) * 2048;   // + tn*2048
    const size_t wg = ((size_t)(ow >> 4)) * 2048;               // + to*2048

    f32x4 a00 = {0.f, 0.f, 0.f, 0.f}, a01 = a00, a10 = a00, a11 = a00;  // [to][tn]

#pragma unroll
    for (int ch = 0; ch < 4; ++ch) {
        const int koff = (ch * 4 + l4) * 128 + l15 * 8;
        const bf16x8 x0h = *(const bf16x8*)(xh + xg + koff);
        const bf16x8 x0m = *(const bf16x8*)(xm + xg + koff);
        const bf16x8 x0l = *(const bf16x8*)(xl + xg + koff);
        const bf16x8 x1h = *(const bf16x8*)(xh + xg + 2048 + koff);
        const bf16x8 x1m = *(const bf16x8*)(xm + xg + 2048 + koff);
        const bf16x8 x1l = *(const bf16x8*)(xl + xg + 2048 + koff);
        const bf16x8 w0h = *(const bf16x8*)(wh + wg + koff);
        const bf16x8 w0m = *(const bf16x8*)(wm + wg + koff);
        const bf16x8 w0l = *(const bf16x8*)(wl + wg + koff);
        const bf16x8 w1h = *(const bf16x8*)(wh + wg + 2048 + koff);
        const bf16x8 w1m = *(const bf16x8*)(wm + wg + 2048 + koff);
        const bf16x8 w1l = *(const bf16x8*)(wl + wg + 2048 + koff);
#define PROD(ACC, WH, WM, WL, XH, XM, XL)                                     \
        ACC = __builtin_amdgcn_mfma_f32_16x16x32_bf16(WH, XH, ACC, 0, 0, 0);  \
        ACC = __builtin_amdgcn_mfma_f32_16x16x32_bf16(WH, XM, ACC, 0, 0, 0);  \
        ACC = __builtin_amdgcn_mfma_f32_16x16x32_bf16(WM, XH, ACC, 0, 0, 0);  \
        ACC = __builtin_amdgcn_mfma_f32_16x16x32_bf16(WM, XM, ACC, 0, 0, 0);  \
        ACC = __builtin_amdgcn_mfma_f32_16x16x32_bf16(WH, XL, ACC, 0, 0, 0);  \
        ACC = __builtin_amdgcn_mfma_f32_16x16x32_bf16(WL, XH, ACC, 0, 0, 0);
        PROD(a00, w0h, w0m, w0l, x0h, x0m, x0l)
        PROD(a01, w0h, w0m, w0l, x1h, x1m, x1l)
        PROD(a10, w1h, w1m, w1l, x0h, x0m, x0l)
        PROD(a11, w1h, w1m, w1l, x1h, x1m, x1l)
#undef PROD
    }
#define EPI(ACC, TO, TN)                                                      \
    {                                                                         \
        const int ob = ow + (TO) * 16 + l4 * 4;                               \
        const int n  = nw + (TN) * 16 + l15;                                  \
        const float rn = rnv[b * 4096 + n];                                   \
        if (ob < 256) {                                                       \
            out[((size_t)(b * 256 + ob + 0)) * 4096 + n] = ACC[0] * rn;       \
            out[((size_t)(b * 256 + ob + 1)) * 4096 + n] = ACC[1] * rn;       \
            out[((size_t)(b * 256 + ob + 2)) * 4096 + n] = ACC[2] * rn;       \
            out[((size_t)(b * 256 + ob + 3)) * 4096 + n] = ACC[3] * rn;       \
        } else {                                                              \
            float4 v = make_float4(ACC[0] * rn, ACC[1] * rn,                  \
                                   ACC[2] * rn, ACC[3] * rn);                 \
            *(float4*)&q[((size_t)(b * 4096 + n)) * 256 + (ob - 256)] = v;    \
        }                                                                     \
    }
    EPI(a00, 0, 0) EPI(a01, 0, 1) EPI(a10, 1, 0) EPI(a11, 1, 1)
#undef EPI
}

// ---- Kernel D: out = relu(P(out) + bias + max_k Q[nn]) in place ----
__global__ __launch_bounds__(256) void gather_kernel(const float* __restrict__ q,
                                                     const int* __restrict__ nn,
                                                     const float* __restrict__ bias,
                                                     float* __restrict__ out) {
    __shared__ int idx[32][9];
    const int b = blockIdx.y, n0 = blockIdx.x * 32;
    const int tid = threadIdx.x;
    for (int t = tid; t < 288; t += 256) {
        int pt = t / 9, k = t - pt * 9;
        idx[pt][k] = nn[(b * 4096 + n0 + pt) * 9 + k];
    }
    __syncthreads();
    const float bv = bias[tid];
    const size_t orow = ((size_t)(b * 256 + tid)) * 4096 + n0;
    float pvals[32];
#pragma unroll
    for (int u = 0; u < 8; ++u)
        *(float4*)&pvals[u * 4] = *(const float4*)&out[orow + u * 4];
    float val[32];
#pragma unroll
    for (int pt = 0; pt < 32; ++pt) {
        float m = -FLT_MAX;
#pragma unroll
        for (int k = 0; k < 9; ++k) {
            int j = idx[pt][k] & 4095;
            m = fmaxf(m, q[((size_t)(b * 4096 + j)) * 256 + tid]);
        }
        float vv = pvals[pt] + bv + m;
        val[pt] = vv > 0.f ? vv : 0.f;
    }
#pragma unroll
    for (int u = 0; u < 8; ++u) {
        float4 v = make_float4(val[u * 4], val[u * 4 + 1], val[u * 4 + 2], val[u * 4 + 3]);
        *(float4*)&out[orow + u * 4] = v;
    }
}

extern "C" void kernel_launch(void* const* d_in, const int* in_sizes, int n_in,
                              void* d_out, int out_size, void* d_ws, size_t ws_size,
                              hipStream_t stream) {
    const float* x    = (const float*)d_in[0];
    const float* w    = (const float*)d_in[1];
    const float* bias = (const float*)d_in[2];
    float* ws = (float*)d_ws;
    float* sq = ws + OFF_SQ;
    float* rn = ws + OFF_RN;
    unsigned short* wh = (unsigned short*)(ws + OFF_WP);
    unsigned short* wm = wh + 65536;
    unsigned short* wl = wm + 65536;
    unsigned short* xh = (unsigned short*)(ws + OFF_A);
    unsigned short* xm = xh + (size_t)CB * CN * CC;
    unsigned short* xl = xm + (size_t)CB * CN * CC;
    u32*   pk = (u32*)(ws + OFF_PK);
    float* q  = ws + OFF_PK;                    // overlays PK (merge precedes pq)
    int*   nn = (int*)(ws + OFF_NN);
    float* out = (float*)d_out;

    prep_kernel  <<<dim3(64, 2),     256, 0, stream>>>(x, sq, rn, xh, xm, xl);
    wprep_kernel <<<dim3(256),       256, 0, stream>>>(w, wh, wm, wl);
    knn_kernel   <<<dim3(16, 64, 2), 256, 0, stream>>>(xh, xm, xl, sq, pk);
    merge_kernel <<<dim3(64),        256, 0, stream>>>(pk, nn);
    pq_kernel    <<<dim3(64, 8, 2),  256, 0, stream>>>(xh, xm, xl, wh, wm, wl, rn, q, out);
    gather_kernel<<<dim3(128, 2),    256, 0, stream>>>(q, nn, bias, out);
}